// Round 2
// baseline (55603.284 us; speedup 1.0000x reference)
//
#include <hip/hip_runtime.h>
#include <cstdint>
#include <cstddef>

#define B_    64
#define T_    1024
#define D_    256
#define H_    512
#define BU_   512
#define GRID_ 256
#define NT_   512

__device__ __forceinline__ float fsigmoid(float x) { return 1.f / (1.f + __expf(-x)); }
__device__ __forceinline__ float ftanh(float x)    { return 2.f / (1.f + __expf(-2.f * x)) - 1.f; }

// Sense-reversing device-wide barrier. cnt at bar[0], gen at bar[32] (separate lines).
// Co-residency of all GRID_ blocks is guaranteed by the cooperative launch.
__device__ __forceinline__ void grid_barrier(unsigned* bar) {
  __syncthreads();
  if (threadIdx.x == 0) {
    unsigned* cnt = bar;
    unsigned* gen = bar + 32;
    unsigned g = __hip_atomic_load(gen, __ATOMIC_RELAXED, __HIP_MEMORY_SCOPE_AGENT);
    __threadfence();  // release my phase's global writes
    unsigned arrived = __hip_atomic_fetch_add(cnt, 1u, __ATOMIC_ACQ_REL, __HIP_MEMORY_SCOPE_AGENT);
    if (arrived == GRID_ - 1) {
      __hip_atomic_store(cnt, 0u, __ATOMIC_RELAXED, __HIP_MEMORY_SCOPE_AGENT);
      __hip_atomic_store(gen, g + 1u, __ATOMIC_RELEASE, __HIP_MEMORY_SCOPE_AGENT);
    } else {
      while (__hip_atomic_load(gen, __ATOMIC_ACQUIRE, __HIP_MEMORY_SCOPE_AGENT) == g) {
        __builtin_amdgcn_s_sleep(1);
      }
    }
    __threadfence();  // acquire other blocks' writes
  }
  __syncthreads();
}

__global__ __launch_bounds__(NT_, 2) void cfc_kernel(
    const float* __restrict__ x,    const float* __restrict__ ts,
    const float* __restrict__ h0,   const float* __restrict__ s0,
    const float* __restrict__ Wbb,  const float* __restrict__ bbb,
    const float* __restrict__ Wff1, const float* __restrict__ bff1,
    const float* __restrict__ Wff2, const float* __restrict__ bff2,
    const float* __restrict__ Wta,  const float* __restrict__ bta,
    const float* __restrict__ Wtb,  const float* __restrict__ btb,
    float* __restrict__ out, float* __restrict__ hws,
    float* __restrict__ bbws, unsigned* __restrict__ bar)
{
  // LDS: per-wave transpose-reduce scratch (stride 66 -> conflict-free float2 reads),
  // per-wave stage-2 sums, and persistent s-state for this block's 2 columns.
  __shared__ float part[8][16][66];   // 33792 B
  __shared__ float sums[8][64];       //  2048 B
  __shared__ float sloc[64][2];       //   512 B

  const int tid  = threadIdx.x;
  const int wv   = tid >> 6;    // 0..7, wave owns rows [wv*8, wv*8+8)
  const int lane = tid & 63;
  const int col0 = blockIdx.x * 2;  // this block's 2 output columns

  // ---- Load this block's weight column slices into registers (one-time gather).
  // k-mapping: k = i*256 + lane*4 + e  (lane-resident fragments aligned with float4
  // activation loads below).
  float w1[2][3][4];  // Wbb: K = 768 (k<256 -> x part, k>=256 -> h part)
  #pragma unroll
  for (int c = 0; c < 2; ++c)
    #pragma unroll
    for (int i = 0; i < 3; ++i)
      #pragma unroll
      for (int e = 0; e < 4; ++e)
        w1[c][i][e] = Wbb[(size_t)(i * 256 + lane * 4 + e) * BU_ + (col0 + c)];

  float w2[4][2][2][4];  // {Wff1,Wff2,Wta,Wtb}: K = 512
  const float* Wm[4] = {Wff1, Wff2, Wta, Wtb};
  #pragma unroll
  for (int m = 0; m < 4; ++m)
    #pragma unroll
    for (int c = 0; c < 2; ++c)
      #pragma unroll
      for (int i = 0; i < 2; ++i)
        #pragma unroll
        for (int e = 0; e < 4; ++e)
          w2[m][c][i][e] = Wm[m][(size_t)(i * 256 + lane * 4 + e) * H_ + (col0 + c)];

  float bb_b[2], fb1[2], fb2[2], fba[2], fbb2[2];
  #pragma unroll
  for (int c = 0; c < 2; ++c) {
    bb_b[c] = bbb[col0 + c];
    fb1[c]  = bff1[col0 + c];
    fb2[c]  = bff2[col0 + c];
    fba[c]  = bta[col0 + c];
    fbb2[c] = btb[col0 + c];
  }

  // ---- Init persistent state: s (LDS) and h workspace (this block's 128-elem slice).
  if (tid < 128) {
    int r = tid >> 1, c = tid & 1;
    sloc[r][c] = s0[r * H_ + col0 + c];
    int idx = blockIdx.x * 128 + tid;
    hws[idx] = h0[idx];
  }
  grid_barrier(bar);  // h workspace fully initialized, barrier counters valid

  for (int t = 0; t < T_; ++t) {
    // ================= Phase 1: bb[:, col0..col0+1] = silu(z @ Wbb + bbb) ==========
    float p[16];  // partials, o = r*2 + c
    #pragma unroll
    for (int o = 0; o < 16; ++o) p[o] = 0.f;

    #pragma unroll
    for (int r = 0; r < 8; ++r) {
      const int row = wv * 8 + r;
      const float4 zx  = ((const float4*)(x + ((size_t)row * T_ + t) * D_))[lane];
      const float4* hrow = (const float4*)(hws + row * H_);
      const float4 zh0 = hrow[lane];
      const float4 zh1 = hrow[lane + 64];
      #pragma unroll
      for (int c = 0; c < 2; ++c) {
        float a;
        a  = zx.x  * w1[c][0][0]; a += zx.y  * w1[c][0][1];
        a += zx.z  * w1[c][0][2]; a += zx.w  * w1[c][0][3];
        a += zh0.x * w1[c][1][0]; a += zh0.y * w1[c][1][1];
        a += zh0.z * w1[c][1][2]; a += zh0.w * w1[c][1][3];
        a += zh1.x * w1[c][2][0]; a += zh1.y * w1[c][2][1];
        a += zh1.z * w1[c][2][2]; a += zh1.w * w1[c][2][3];
        p[r * 2 + c] = a;
      }
    }

    // wave-local transpose-reduce (no __syncthreads needed: per-wave LDS region,
    // same-wave DS ops are ordered)
    #pragma unroll
    for (int o = 0; o < 16; ++o) part[wv][o][lane] = p[o];
    if (lane < 16) {
      const float2* pp = (const float2*)(&part[wv][lane][0]);
      float se = 0.f, so = 0.f;
      #pragma unroll
      for (int i = 0; i < 32; ++i) { float2 v = pp[i]; se += v.x; so += v.y; }
      const float pre = se + so + bb_b[lane & 1];
      const float bbv = pre * fsigmoid(pre);  // silu
      const int row = wv * 8 + (lane >> 1);
      bbws[row * BU_ + col0 + (lane & 1)] = bbv;
    }
    grid_barrier(bar);  // bb globally visible

    // ===== Phase 2: ff1/ff2/ta/tb for h-cols {col0,col0+1}, then recurrence ========
    #pragma unroll
    for (int b = 0; b < 4; ++b) {  // 2 rows per batch (partial-register pressure)
      float q[16];  // o = rr*8 + c*4 + m
      #pragma unroll
      for (int o = 0; o < 16; ++o) q[o] = 0.f;
      #pragma unroll
      for (int rr = 0; rr < 2; ++rr) {
        const int row = wv * 8 + b * 2 + rr;
        const float4* brow = (const float4*)(bbws + row * BU_);
        const float4 v0 = brow[lane];
        const float4 v1 = brow[lane + 64];
        #pragma unroll
        for (int c = 0; c < 2; ++c)
          #pragma unroll
          for (int m = 0; m < 4; ++m) {
            float a;
            a  = v0.x * w2[m][c][0][0]; a += v0.y * w2[m][c][0][1];
            a += v0.z * w2[m][c][0][2]; a += v0.w * w2[m][c][0][3];
            a += v1.x * w2[m][c][1][0]; a += v1.y * w2[m][c][1][1];
            a += v1.z * w2[m][c][1][2]; a += v1.w * w2[m][c][1][3];
            q[rr * 8 + c * 4 + m] = a;
          }
      }
      #pragma unroll
      for (int o = 0; o < 16; ++o) part[wv][o][lane] = q[o];
      if (lane < 16) {
        const float2* pp = (const float2*)(&part[wv][lane][0]);
        float se = 0.f, so = 0.f;
        #pragma unroll
        for (int i = 0; i < 32; ++i) { float2 v = pp[i]; se += v.x; so += v.y; }
        sums[wv][b * 16 + lane] = se + so;
      }
    }

    if (lane < 16) {
      const int rl = lane >> 1, c = lane & 1;
      const int row = wv * 8 + rl;
      // batch = rl>>1, rr = rl&1 -> 4 mats contiguous
      const float4 Sm = *(const float4*)&sums[wv][(rl >> 1) * 16 + (rl & 1) * 8 + c * 4];
      const float tsv = ts[row * T_ + t];
      const float tsn = 1.f / tsv;  // always > 0 here (ts in [0.5, 2])
      const float wts = __expf(tsn * (1.f - 2.f * __logf(tsn)));
      const float f1  = ftanh(Sm.x + fb1[c]);
      const float f2  = ftanh(Sm.y + fb2[c]);
      const float tav = Sm.z + fba[c];
      const float tbv = Sm.w + fbb2[c];
      float sv = sloc[row][c] + tav * wts + tbv;
      sloc[row][c] = sv;
      const float ti = fsigmoid(sv);
      const float hn = f1 + ti * (f2 - f1);
      const int col = col0 + c;
      hws[row * H_ + col] = hn;
      out[((size_t)row * T_ + t) * H_ + col] = hn;
    }
    grid_barrier(bar);  // h globally visible for next step
  }
}

extern "C" void kernel_launch(void* const* d_in, const int* in_sizes, int n_in,
                              void* d_out, int out_size, void* d_ws, size_t ws_size,
                              hipStream_t stream) {
  const float* x    = (const float*)d_in[0];
  const float* ts   = (const float*)d_in[1];
  const float* h0   = (const float*)d_in[2];
  const float* s0   = (const float*)d_in[3];
  const float* Wbb  = (const float*)d_in[4];
  const float* bbb  = (const float*)d_in[5];
  const float* Wff1 = (const float*)d_in[6];
  const float* bff1 = (const float*)d_in[7];
  const float* Wff2 = (const float*)d_in[8];
  const float* bff2 = (const float*)d_in[9];
  const float* Wta  = (const float*)d_in[10];
  const float* bta  = (const float*)d_in[11];
  const float* Wtb  = (const float*)d_in[12];
  const float* btb  = (const float*)d_in[13];
  float* out = (float*)d_out;

  // ws layout: [0,4096): barrier counters; then h (128 KB); then bb (128 KB).
  unsigned* bar = (unsigned*)d_ws;
  float* hws  = (float*)((char*)d_ws + 4096);
  float* bbws = hws + B_ * H_;

  // Barrier state must be zeroed every launch (ws is re-poisoned to 0xAA).
  hipMemsetAsync(d_ws, 0, 4096, stream);

  void* args[] = {
      (void*)&x, (void*)&ts, (void*)&h0, (void*)&s0,
      (void*)&Wbb, (void*)&bbb, (void*)&Wff1, (void*)&bff1,
      (void*)&Wff2, (void*)&bff2, (void*)&Wta, (void*)&bta,
      (void*)&Wtb, (void*)&btb, (void*)&out, (void*)&hws,
      (void*)&bbws, (void*)&bar};

  hipLaunchCooperativeKernel((const void*)cfc_kernel, dim3(GRID_), dim3(NT_),
                             args, 0, stream);
}

// Round 3
// 20633.691 us; speedup vs baseline: 2.6948x; 2.6948x over previous
//
#include <hip/hip_runtime.h>
#include <cstdint>
#include <cstddef>

#define B_    64
#define T_    1024
#define D_    256
#define H_    512
#define BU_   512
#define GRID_ 256
#define NT_   512

__device__ __forceinline__ float fsigmoid(float x) { return 1.f / (1.f + __expf(-x)); }
__device__ __forceinline__ float ftanh(float x)    { return 2.f / (1.f + __expf(-2.f * x)) - 1.f; }

// Relaxed agent-scope atomic store: compiles to an sc0/sc1 write-through store —
// visible at the L3 coherence point once vmcnt-drained, never dirty in any L2.
__device__ __forceinline__ void astore(float* p, float v) {
  union { float f; unsigned u; } c; c.f = v;
  __hip_atomic_store((unsigned*)p, c.u, __ATOMIC_RELAXED, __HIP_MEMORY_SCOPE_AGENT);
}

// Fence-free two-level barrier. 16 leaves x 16 blocks -> root(16) -> gen.
// No acq/rel fences (no buffer_wbl2). Ordering argument:
//   producer: sc0sc1 data stores -> s_waitcnt vmcnt(0) (data at L3) -> leaf RMW.
//   leaf-last's RMW result observed => all 16 producers' data committed at L3;
//   chain continues through root RMW -> gen store (each dependent on prior RMW
//   result, so HW-ordered). Consumer: polls gen (reads L3), then ONE
//   buffer_inv sc1 (tag invalidate: clean stale bb/h lines out of L1/L2; no
//   dirty exchange data exists, out-dirty lines are preserved), then normal
//   cached loads observe fresh data.
__device__ __forceinline__ void grid_barrier(unsigned* bar) {
  __syncthreads();
  if (threadIdx.x == 0) {
    unsigned* leaf = bar + ((blockIdx.x >> 4) << 6);  // 256 B apart
    unsigned* root = bar + 1024;
    unsigned* gen  = bar + 1088;
    unsigned g = __hip_atomic_load(gen, __ATOMIC_RELAXED, __HIP_MEMORY_SCOPE_AGENT);
    __builtin_amdgcn_s_waitcnt(0);  // drain my sc0sc1 data stores to L3
    asm volatile("" ::: "memory");
    unsigned a = __hip_atomic_fetch_add(leaf, 1u, __ATOMIC_RELAXED, __HIP_MEMORY_SCOPE_AGENT);
    bool done = false;
    if (a == 15u) {
      __hip_atomic_store(leaf, 0u, __ATOMIC_RELAXED, __HIP_MEMORY_SCOPE_AGENT);
      unsigned b = __hip_atomic_fetch_add(root, 1u, __ATOMIC_RELAXED, __HIP_MEMORY_SCOPE_AGENT);
      if (b == 15u) {
        __hip_atomic_store(root, 0u, __ATOMIC_RELAXED, __HIP_MEMORY_SCOPE_AGENT);
        __hip_atomic_store(gen, g + 1u, __ATOMIC_RELAXED, __HIP_MEMORY_SCOPE_AGENT);
        done = true;
      }
    }
    if (!done) {
      while (__hip_atomic_load(gen, __ATOMIC_RELAXED, __HIP_MEMORY_SCOPE_AGENT) == g)
        __builtin_amdgcn_s_sleep(1);
    }
    // invalidate stale clean lines (L1+L2); dirty (out) lines are preserved.
    asm volatile("buffer_inv sc1\n\ts_waitcnt vmcnt(0)" ::: "memory");
  }
  __syncthreads();
}

__global__ __launch_bounds__(NT_, 2) void cfc_kernel(
    const float* __restrict__ x,    const float* __restrict__ ts,
    const float* __restrict__ h0,   const float* __restrict__ s0,
    const float* __restrict__ Wbb,  const float* __restrict__ bbb,
    const float* __restrict__ Wff1, const float* __restrict__ bff1,
    const float* __restrict__ Wff2, const float* __restrict__ bff2,
    const float* __restrict__ Wta,  const float* __restrict__ bta,
    const float* __restrict__ Wtb,  const float* __restrict__ btb,
    float* __restrict__ out, float* __restrict__ hws,
    float* __restrict__ bbws, unsigned* __restrict__ bar)
{
  __shared__ float part[8][16][66];   // 33792 B, stride 66 -> conflict-free
  __shared__ float sums[8][64];       //  2048 B
  __shared__ float sloc[64][2];       //   512 B

  const int tid  = threadIdx.x;
  const int wv   = tid >> 6;
  const int lane = tid & 63;
  const int col0 = blockIdx.x * 2;

  // ---- weights into registers (one-time; k = i*256 + lane*4 + e)
  float w1[2][3][4];
  #pragma unroll
  for (int c = 0; c < 2; ++c)
    #pragma unroll
    for (int i = 0; i < 3; ++i)
      #pragma unroll
      for (int e = 0; e < 4; ++e)
        w1[c][i][e] = Wbb[(size_t)(i * 256 + lane * 4 + e) * BU_ + (col0 + c)];

  float w2[4][2][2][4];
  const float* Wm[4] = {Wff1, Wff2, Wta, Wtb};
  #pragma unroll
  for (int m = 0; m < 4; ++m)
    #pragma unroll
    for (int c = 0; c < 2; ++c)
      #pragma unroll
      for (int i = 0; i < 2; ++i)
        #pragma unroll
        for (int e = 0; e < 4; ++e)
          w2[m][c][i][e] = Wm[m][(size_t)(i * 256 + lane * 4 + e) * H_ + (col0 + c)];

  float bb_b[2], fb1[2], fb2[2], fba[2], fbb2[2];
  #pragma unroll
  for (int c = 0; c < 2; ++c) {
    bb_b[c] = bbb[col0 + c];
    fb1[c]  = bff1[col0 + c];
    fb2[c]  = bff2[col0 + c];
    fba[c]  = bta[col0 + c];
    fbb2[c] = btb[col0 + c];
  }

  if (tid < 128) {
    int r = tid >> 1, c = tid & 1;
    sloc[r][c] = s0[r * H_ + col0 + c];
    int idx = blockIdx.x * 128 + tid;
    astore(hws + idx, h0[idx]);
  }
  grid_barrier(bar);

  for (int t = 0; t < T_; ++t) {
    // ============ Phase 1: bb[:, col0..+1] = silu(z @ Wbb + bbb) ============
    float p[16];
    #pragma unroll
    for (int o = 0; o < 16; ++o) p[o] = 0.f;

    #pragma unroll
    for (int r = 0; r < 8; ++r) {
      const int row = wv * 8 + r;
      const float4 zx  = ((const float4*)(x + ((size_t)row * T_ + t) * D_))[lane];
      const float4* hrow = (const float4*)(hws + row * H_);
      const float4 zh0 = hrow[lane];
      const float4 zh1 = hrow[lane + 64];
      // Deferred coalesced out-write: block `row` owns out[row]; its wave
      // row>>3 already holds h(t-1)[row][:] spread across lanes -> full-line
      // float4 stores (single writer, no partial-line amplification).
      if (blockIdx.x == row && t > 0) {
        float4* op = (float4*)(out + ((size_t)row * T_ + (t - 1)) * H_);
        op[lane]      = zh0;
        op[lane + 64] = zh1;
      }
      #pragma unroll
      for (int c = 0; c < 2; ++c) {
        float a;
        a  = zx.x  * w1[c][0][0]; a += zx.y  * w1[c][0][1];
        a += zx.z  * w1[c][0][2]; a += zx.w  * w1[c][0][3];
        a += zh0.x * w1[c][1][0]; a += zh0.y * w1[c][1][1];
        a += zh0.z * w1[c][1][2]; a += zh0.w * w1[c][1][3];
        a += zh1.x * w1[c][2][0]; a += zh1.y * w1[c][2][1];
        a += zh1.z * w1[c][2][2]; a += zh1.w * w1[c][2][3];
        p[r * 2 + c] = a;
      }
    }

    #pragma unroll
    for (int o = 0; o < 16; ++o) part[wv][o][lane] = p[o];
    if (lane < 16) {
      const float2* pp = (const float2*)(&part[wv][lane][0]);
      float se = 0.f, so = 0.f;
      #pragma unroll
      for (int i = 0; i < 32; ++i) { float2 v = pp[i]; se += v.x; so += v.y; }
      const float pre = se + so + bb_b[lane & 1];
      const float bbv = pre * fsigmoid(pre);
      const int row = wv * 8 + (lane >> 1);
      astore(bbws + row * BU_ + col0 + (lane & 1), bbv);
    }
    grid_barrier(bar);  // bb at L3, caches invalidated

    // ============ Phase 2: four mats + recurrence ============
    #pragma unroll
    for (int b = 0; b < 4; ++b) {
      float q[16];
      #pragma unroll
      for (int o = 0; o < 16; ++o) q[o] = 0.f;
      #pragma unroll
      for (int rr = 0; rr < 2; ++rr) {
        const int row = wv * 8 + b * 2 + rr;
        const float4* brow = (const float4*)(bbws + row * BU_);
        const float4 v0 = brow[lane];
        const float4 v1 = brow[lane + 64];
        #pragma unroll
        for (int c = 0; c < 2; ++c)
          #pragma unroll
          for (int m = 0; m < 4; ++m) {
            float a;
            a  = v0.x * w2[m][c][0][0]; a += v0.y * w2[m][c][0][1];
            a += v0.z * w2[m][c][0][2]; a += v0.w * w2[m][c][0][3];
            a += v1.x * w2[m][c][1][0]; a += v1.y * w2[m][c][1][1];
            a += v1.z * w2[m][c][1][2]; a += v1.w * w2[m][c][1][3];
            q[rr * 8 + c * 4 + m] = a;
          }
      }
      #pragma unroll
      for (int o = 0; o < 16; ++o) part[wv][o][lane] = q[o];
      if (lane < 16) {
        const float2* pp = (const float2*)(&part[wv][lane][0]);
        float se = 0.f, so = 0.f;
        #pragma unroll
        for (int i = 0; i < 32; ++i) { float2 v = pp[i]; se += v.x; so += v.y; }
        sums[wv][b * 16 + lane] = se + so;
      }
    }

    if (lane < 16) {
      const int rl = lane >> 1, c = lane & 1;
      const int row = wv * 8 + rl;
      const float4 Sm = *(const float4*)&sums[wv][(rl >> 1) * 16 + (rl & 1) * 8 + c * 4];
      const float tsv = ts[row * T_ + t];
      const float tsn = 1.f / tsv;
      const float wts = __expf(tsn * (1.f - 2.f * __logf(tsn)));
      const float f1  = ftanh(Sm.x + fb1[c]);
      const float f2  = ftanh(Sm.y + fb2[c]);
      const float tav = Sm.z + fba[c];
      const float tbv = Sm.w + fbb2[c];
      float sv = sloc[row][c] + tav * wts + tbv;
      sloc[row][c] = sv;
      const float ti = fsigmoid(sv);
      const float hn = f1 + ti * (f2 - f1);
      astore(hws + row * H_ + col0 + c, hn);
    }
    grid_barrier(bar);  // h at L3, caches invalidated
  }

  // Tail: out[:, T-1, :] = h(T-1)
  if (blockIdx.x < 64 && wv == (blockIdx.x >> 3)) {
    const int row = blockIdx.x;
    const float4* hrow = (const float4*)(hws + row * H_);
    const float4 a0 = hrow[lane];
    const float4 a1 = hrow[lane + 64];
    float4* op = (float4*)(out + ((size_t)row * T_ + (T_ - 1)) * H_);
    op[lane]      = a0;
    op[lane + 64] = a1;
  }
}

extern "C" void kernel_launch(void* const* d_in, const int* in_sizes, int n_in,
                              void* d_out, int out_size, void* d_ws, size_t ws_size,
                              hipStream_t stream) {
  const float* x    = (const float*)d_in[0];
  const float* ts   = (const float*)d_in[1];
  const float* h0   = (const float*)d_in[2];
  const float* s0   = (const float*)d_in[3];
  const float* Wbb  = (const float*)d_in[4];
  const float* bbb  = (const float*)d_in[5];
  const float* Wff1 = (const float*)d_in[6];
  const float* bff1 = (const float*)d_in[7];
  const float* Wff2 = (const float*)d_in[8];
  const float* bff2 = (const float*)d_in[9];
  const float* Wta  = (const float*)d_in[10];
  const float* bta  = (const float*)d_in[11];
  const float* Wtb  = (const float*)d_in[12];
  const float* btb  = (const float*)d_in[13];
  float* out = (float*)d_out;

  // ws layout: [0,8192): barrier tree; then h (128 KB); then bb (128 KB).
  unsigned* bar = (unsigned*)d_ws;
  float* hws  = (float*)((char*)d_ws + 8192);
  float* bbws = hws + B_ * H_;

  hipMemsetAsync(d_ws, 0, 8192, stream);

  void* args[] = {
      (void*)&x, (void*)&ts, (void*)&h0, (void*)&s0,
      (void*)&Wbb, (void*)&bbb, (void*)&Wff1, (void*)&bff1,
      (void*)&Wff2, (void*)&bff2, (void*)&Wta, (void*)&bta,
      (void*)&Wtb, (void*)&btb, (void*)&out, (void*)&hws,
      (void*)&bbws, (void*)&bar};

  hipLaunchCooperativeKernel((const void*)cfc_kernel, dim3(GRID_), dim3(NT_),
                             args, 0, stream);
}